// Round 13
// baseline (164.901 us; speedup 1.0000x reference)
//
#include <hip/hip_runtime.h>

typedef float f4v __attribute__((ext_vector_type(4)));
typedef _Float16 h2v __attribute__((ext_vector_type(2)));
typedef _Float16 h4v __attribute__((ext_vector_type(4)));
typedef _Float16 h8v __attribute__((ext_vector_type(8)));
typedef __fp16 g4 __attribute__((ext_vector_type(4)));
typedef __fp16 g8 __attribute__((ext_vector_type(8)));
typedef unsigned short u16;
typedef unsigned int u32;

// B=2, T=192, C=512, H=8, HS=64, ORDER=3; scale = 1/sqrt(64) = 0.125
#define SPLIT 8
#define ESC 0.18033688011112042f  // 0.125 * log2(e), folded into Q at proj

__device__ __forceinline__ h2v pkh(float lo, float hi) {
  return __builtin_bit_cast(h2v, __builtin_amdgcn_cvt_pkrtz(lo, hi));
}
__device__ __forceinline__ f4v mfma_k32(h8v a, h8v b, f4v c) {
  return __builtin_amdgcn_mfma_f32_16x16x32_f16(
      __builtin_bit_cast(g8, a), __builtin_bit_cast(g8, b), c, 0, 0, 0);
}
__device__ __forceinline__ f4v mfma_k16(h4v a, h4v b, f4v c) {
  return __builtin_amdgcn_mfma_f32_16x16x16f16(
      __builtin_bit_cast(g4, a), __builtin_bit_cast(g4, b), c, 0, 0, 0);
}

// ---------------- projection kernel ----------------
// grid = 5 slots * 16 bh * 6 t-tiles * 2 n-halves = 960 blocks, 256 thr.
// Tile 32(t) x 32(d), K=512.  n-split doubles blocks/CU (1.9 -> 3.75) to
// cover the per-kc barrier drains (r12 analysis: proj+outproj ~65us,
// stall-bound at low occupancy).  BIT-EXACT: each output's c-ascending
// f32 accumulation chain is unchanged; only the tile->block map changed.
__global__ __launch_bounds__(256) void proj_kernel(
    const float* __restrict__ x0, const float* __restrict__ x1,
    const float* __restrict__ x2,
    const float* __restrict__ qw, const float* __restrict__ qb,
    const float* __restrict__ kw, const float* __restrict__ kb,
    const float* __restrict__ vw, const float* __restrict__ vb,
    u16* __restrict__ Q0h, u16* __restrict__ K1h, float* __restrict__ V1f,
    u16* __restrict__ K2b, u16* __restrict__ V2b) {
  __shared__ float xs[32][36];   // [c][m]
  __shared__ float wsh[32][36];  // [c][n] (32-wide half)

  int bx = blockIdx.x;
  int slot = bx / 192;
  int rem = bx - slot * 192;
  int bh = rem / 12;
  int r2 = rem - bh * 12;
  int tt = r2 >> 1;
  int n0 = (r2 & 1) * 32;
  int b = bh >> 3, h = bh & 7;
  int t0 = tt * 32;

  const float* x; const float* w; const float* bias; int o;
  float* outf = nullptr; u16* outb = nullptr;
  switch (slot) {
    case 0: x = x0; w = qw; bias = qb; o = 0; outb = Q0h; break;
    case 1: x = x1; w = kw; bias = kb; o = 1; outb = K1h; break;
    case 2: x = x2; w = kw; bias = kb; o = 2; outb = K2b; break;
    case 3: x = x1; w = vw; bias = vb; o = 1; outf = V1f; break;
    default: x = x2; w = vw; bias = vb; o = 2; outb = V2b; break;
  }
  x += b * 192 * 512;
  w += (h * 3 + o) * 64 * 512 + n0 * 512;
  bias += (h * 3 + o) * 64 + n0;

  int tid = threadIdx.x;
  int m2 = tid >> 4, nq = tid & 15;
  int mA = tid >> 3, clA = (tid & 7) * 4;  // stage coords (32 rows x 32 c)
  float acc[2][2] = {};

  float4 pX, pW0;  // prefetch registers
  pX = *(const float4*)(x + (t0 + mA) * 512 + clA);
  pW0 = *(const float4*)(w + mA * 512 + clA);

  for (int kc = 0; kc < 16; ++kc) {
    xs[clA][mA] = pX.x; xs[clA + 1][mA] = pX.y;
    xs[clA + 2][mA] = pX.z; xs[clA + 3][mA] = pX.w;
    wsh[clA][mA] = pW0.x; wsh[clA + 1][mA] = pW0.y;
    wsh[clA + 2][mA] = pW0.z; wsh[clA + 3][mA] = pW0.w;
    __syncthreads();
    if (kc < 15) {  // prefetch next tile; latency hidden by compute below
      int cb0 = (kc + 1) * 32;
      pX = *(const float4*)(x + (t0 + mA) * 512 + cb0 + clA);
      pW0 = *(const float4*)(w + mA * 512 + cb0 + clA);
    }
#pragma unroll
    for (int c = 0; c < 32; ++c) {
      float2 av = *(const float2*)&xs[c][m2 * 2];
      float2 bv = *(const float2*)&wsh[c][nq * 2];
      acc[0][0] += av.x * bv.x; acc[0][1] += av.x * bv.y;
      acc[1][0] += av.y * bv.x; acc[1][1] += av.y * bv.y;
    }
    __syncthreads();
  }

  float2 bias2 = *(const float2*)(bias + nq * 2);
#pragma unroll
  for (int i = 0; i < 2; ++i) {
    int t = t0 + m2 * 2 + i;
    long base = ((long)(bh * 192 + t)) * 64 + n0 + nq * 2;
    float o0 = acc[i][0] + bias2.x;
    float o1 = acc[i][1] + bias2.y;
    if (slot == 0) {  // fold attention scale+log2e into Q
      o0 *= ESC; o1 *= ESC;
    }
    if (outf) {
      float2 st = {o0, o1};
      *(float2*)(outf + base) = st;
    } else {
      h2v a = pkh(o0, o1);
      *(u32*)(outb + base) = __builtin_bit_cast(u32, a);
    }
  }
}

// ---------------- attention kernel ----------------
// grid = SPLIT*16*12 = 1536 blocks, 256 threads (4 waves), LDS = 25856 B.
// BYTE-IDENTICAL to the round-12 PASS (single S/P chain; ILP-doubling
// variants miscompile -- rounds 3/4/7/8).  See r12 notes: operand-swapped
// scores keep P in registers; V2T region recycled for K1/V1 LDS stage.
__global__ __launch_bounds__(256, 4) void attn_kernel(
    const u16* __restrict__ Q0h, const u16* __restrict__ K1h,
    const float* __restrict__ V1f, const u16* __restrict__ K2b,
    const u16* __restrict__ V2b, float* __restrict__ Op,
    float* __restrict__ lp) {
  __shared__ __align__(16) char smem[25856];
  int bx = blockIdx.x;
  int sp = bx / 192;
  int rem = bx - sp * 192;
  int bh = rem / 12;
  int itile = rem - bh * 12;
  int i0 = itile * 16;
  int js = sp * 24;
  int tid = threadIdx.x;
  int wave = tid >> 6;
  int lane = tid & 63;
  int l15 = lane & 15;
  int quad = lane >> 4;

  // K1s/V1s live in the recycled V2T region after the v2g reads.
  u16* K1s = (u16*)smem;                // [24 j][64 d] u16 f16, 3072 B
  float* V1s = (float*)(smem + 3072);   // [24 j][64 d] f32, 6144 B

  // ---- early register staging of K1/V1 (latency overlaps V2T stage)
  u32 kreg0, kreg1, kreg2;
  float2 vreg0, vreg1, vreg2;
  {
    const u32* ksrc = (const u32*)(K1h + (bh * 192 + js) * 64);  // 768 u32
    kreg0 = ksrc[tid]; kreg1 = ksrc[256 + tid]; kreg2 = ksrc[512 + tid];
    const float2* vsrc2 = (const float2*)(V1f + (bh * 192 + js) * 64);
    vreg0 = vsrc2[tid]; vreg1 = vsrc2[256 + tid]; vreg2 = vsrc2[512 + tid];
  }

  // ---- prologue: stage V2^T [64 d][202 pad] u16 (natural k order)
  u16* V2T = (u16*)smem;
  {
    const u32* vsrc = (const u32*)V2b + bh * 6144;
#pragma unroll
    for (int r = 0; r < 24; ++r) {
      int idx = r * 256 + tid;
      int k = idx >> 5, d2 = idx & 31;
      u32 v = vsrc[idx];
      V2T[(d2 * 2) * 202 + k] = (u16)v;
      V2T[(d2 * 2 + 1) * 202 + k] = (u16)(v >> 16);
    }
  }
  // K2 A-fragments straight from global (rows k = w*48+nt*16+l15, kdim d)
  h8v k2f[3][2];
#pragma unroll
  for (int nt = 0; nt < 3; ++nt)
#pragma unroll
    for (int ks = 0; ks < 2; ++ks)
      k2f[nt][ks] = *(const h8v*)(K2b +
          (bh * 192 + wave * 48 + nt * 16 + l15) * 64 + ks * 32 + quad * 8);
  // Q B-fragments (kdim d = quad*8+idx (+32), col i = l15), pre-scaled ESC
  const u16* qq = Q0h + (bh * 192 + i0 + l15) * 64 + quad * 8;
  h8v qh0 = *(const h8v*)qq;
  h8v qh1 = *(const h8v*)(qq + 32);
  __syncthreads();
  // V2 B-frags for PV: grp0 k = w48+{quad*4+0..3, 16+quad*4+0..3},
  // grp1 k = w48+32+quad*4+0..3; col d = dt*16+l15.  u32 reads (stride
  // 404 B is only 4B-aligned for odd d).
  h8v v2g0[4]; h4v v2g1[4];
#pragma unroll
  for (int dt = 0; dt < 4; ++dt) {
    const char* p = smem + (dt * 16 + l15) * 404 + wave * 96 + quad * 8;
    union { h8v v; u32 w[4]; } u0;
    u0.w[0] = *(const u32*)p;        u0.w[1] = *(const u32*)(p + 4);
    u0.w[2] = *(const u32*)(p + 32); u0.w[3] = *(const u32*)(p + 36);
    v2g0[dt] = u0.v;
    union { h4v v; u32 w[2]; } u1;
    u1.w[0] = *(const u32*)(p + 64); u1.w[1] = *(const u32*)(p + 68);
    v2g1[dt] = u1.v;
  }
  __syncthreads();  // v2g in regs; V2T region now dead -> recycle
  // write K1/V1 from staging registers into the recycled region
  ((u32*)K1s)[tid] = kreg0;
  ((u32*)K1s)[256 + tid] = kreg1;
  ((u32*)K1s)[512 + tid] = kreg2;
  ((float2*)V1s)[tid] = vreg0;
  ((float2*)V1s)[256 + tid] = vreg1;
  ((float2*)V1s)[512 + tid] = vreg2;
  __syncthreads();  // K1s/V1s staged

  f4v Oacc[4] = {};
  float lsum = 0.f;
  const f4v z = {0.f, 0.f, 0.f, 0.f};

#pragma unroll 1
  for (int j = 0; j < 24; ++j) {
    // B-frag of S^T: Q~[i,d]*K1[j,d] via packed f16 mul (K1 from LDS)
    h8v c0 = *(const h8v*)(K1s + j * 64 + quad * 8);
    h8v c1 = *(const h8v*)(K1s + j * 64 + 32 + quad * 8);
    h8v B0 = qh0 * c0, B1 = qh1 * c1;
    // S^T[k=w48+nt*16+quad*4+r][i=l15], sum over d=0..63
    f4v s0 = mfma_k32(k2f[0][0], B0, z);
    f4v s1 = mfma_k32(k2f[1][0], B0, z);
    f4v s2 = mfma_k32(k2f[2][0], B0, z);
    s0 = mfma_k32(k2f[0][1], B1, s0);
    s1 = mfma_k32(k2f[1][1], B1, s1);
    s2 = mfma_k32(k2f[2][1], B1, s2);
    float p[12];
#pragma unroll
    for (int r = 0; r < 4; ++r) {
      p[r] = __builtin_amdgcn_exp2f(s0[r]);
      p[4 + r] = __builtin_amdgcn_exp2f(s1[r]);
      p[8 + r] = __builtin_amdgcn_exp2f(s2[r]);
    }
    lsum += (((p[0] + p[1]) + (p[2] + p[3])) + ((p[4] + p[5]) + (p[6] + p[7]))) +
            ((p[8] + p[9]) + (p[10] + p[11]));
    // P already in A-fragment layout: row i=l15, k in (quad, idx)
    union { h8v v; h2v h[4]; } pa0;
    pa0.h[0] = pkh(p[0], p[1]);  pa0.h[1] = pkh(p[2], p[3]);
    pa0.h[2] = pkh(p[4], p[5]);  pa0.h[3] = pkh(p[6], p[7]);
    union { h4v v; h2v h[2]; } pa1;
    pa1.h[0] = pkh(p[8], p[9]);  pa1.h[1] = pkh(p[10], p[11]);
    float v1r0 = V1s[j * 64 + l15];
    float v1r1 = V1s[j * 64 + 16 + l15];
    float v1r2 = V1s[j * 64 + 32 + l15];
    float v1r3 = V1s[j * 64 + 48 + l15];
    // W_j[i,d] over this wave's 48 k, then O += V1[j,d]*W_j
#pragma unroll
    for (int dt = 0; dt < 4; ++dt) {
      f4v w = mfma_k32(pa0.v, v2g0[dt], z);
      w = mfma_k16(pa1.v, v2g1[dt], w);
      float v1x = dt == 0 ? v1r0 : dt == 1 ? v1r1 : dt == 2 ? v1r2 : v1r3;
      Oacc[dt][0] = fmaf(v1x, w[0], Oacc[dt][0]);
      Oacc[dt][1] = fmaf(v1x, w[1], Oacc[dt][1]);
      Oacc[dt][2] = fmaf(v1x, w[2], Oacc[dt][2]);
      Oacc[dt][3] = fmaf(v1x, w[3], Oacc[dt][3]);
    }
  }

  // ---- epilogue: cross-wave k-slice reduction of O and l
  __syncthreads();  // all waves done; smem free
  float* ored = (float*)smem;            // 4 waves x [16 i][64 d] f32
  float* lred = (float*)(smem + 16384);  // 64 f32
  float* ow = ored + wave * 1024;
#pragma unroll
  for (int dt = 0; dt < 4; ++dt)
#pragma unroll
    for (int r = 0; r < 4; ++r)
      ow[(quad * 4 + r) * 64 + dt * 16 + l15] = Oacc[dt][r];
  lsum += __shfl_xor(lsum, 16);
  lsum += __shfl_xor(lsum, 32);
  if (quad == 0) lred[wave * 16 + l15] = lsum;
  __syncthreads();
  f4v s = *(const f4v*)(ored + tid * 4);
  s += *(const f4v*)(ored + 1024 + tid * 4);
  s += *(const f4v*)(ored + 2048 + tid * 4);
  s += *(const f4v*)(ored + 3072 + tid * 4);
  *(f4v*)(Op + ((long)(sp * 16 + bh) * 192 + i0) * 64 + tid * 4) = s;
  if (tid < 16)
    lp[(sp * 16 + bh) * 192 + i0 + tid] =
        lred[tid] + lred[16 + tid] + lred[32 + tid] + lred[48 + tid];
}

// ---------------- output projection (split-combine + 1/l fused) ----------
// grid = 24 mt(16) * 32 nt(16) = 768 blocks (was 192 = 0.75 blocks/CU --
// the occupancy hole).  n-split 4: BIT-EXACT (each output's kc chain and
// the combine/linv math are unchanged).
__global__ __launch_bounds__(256) void outproj_kernel(
    const float* __restrict__ Op, const float* __restrict__ lp,
    const float* __restrict__ cw, const float* __restrict__ cb,
    float* __restrict__ out) {
  __shared__ float xs[32][20];   // [c][m]
  __shared__ float wsh[32][20];  // [c][n] (16-wide)
  __shared__ float linv[8][16];  // [h][m]
  int bx = blockIdx.x;
  int mt = bx >> 5, nt = bx & 31;
  int m0 = mt * 16;
  int b = m0 / 192;
  int t0 = m0 - b * 192;
  int n0 = nt * 16;
  int tid = threadIdx.x;

  if (tid < 128) {
    int h = tid >> 4, ml = tid & 15;
    float s = 0.f;
#pragma unroll
    for (int sp = 0; sp < SPLIT; ++sp)
      s += lp[(sp * 16 + b * 8 + h) * 192 + t0 + ml];
    linv[h][ml] = 1.0f / s;
  }

  int mA = tid >> 3, clA = (tid & 7) * 4;   // A-stage (tid<128 only)
  int nB = tid >> 4, cl2 = (tid & 15) * 2;  // B-stage: 16 rows x 32 c
  int m = tid >> 4, nq = tid & 15;
  float acc = 0.f;

  float4 pA[SPLIT];
  float2 pW0;
  {  // prefetch kc = 0 (h=0, d0=0)
    if (tid < 128) {
#pragma unroll
      for (int sp = 0; sp < SPLIT; ++sp)
        pA[sp] = *(const float4*)(
            Op + (long)((sp * 16 + b * 8) * 192 + t0 + mA) * 64 + clA);
    }
    pW0 = *(const float2*)(cw + (long)(n0 + nB) * 512 + cl2);
  }
  __syncthreads();  // linv ready

  for (int kc = 0; kc < 16; ++kc) {
    int h = kc >> 1;
    if (tid < 128) {  // combine SPLIT partials, scale 1/l, store [c][m]
      float4 s = pA[0];
#pragma unroll
      for (int sp = 1; sp < SPLIT; ++sp) {
        s.x += pA[sp].x; s.y += pA[sp].y; s.z += pA[sp].z; s.w += pA[sp].w;
      }
      float li = linv[h][mA];
      xs[clA][mA] = s.x * li; xs[clA + 1][mA] = s.y * li;
      xs[clA + 2][mA] = s.z * li; xs[clA + 3][mA] = s.w * li;
    }
    wsh[cl2][nB] = pW0.x; wsh[cl2 + 1][nB] = pW0.y;
    __syncthreads();
    if (kc < 15) {  // prefetch next kc during compute
      int h2 = (kc + 1) >> 1, d2 = ((kc + 1) & 1) * 32;
      if (tid < 128) {
#pragma unroll
        for (int sp = 0; sp < SPLIT; ++sp)
          pA[sp] = *(const float4*)(
              Op + (long)((sp * 16 + b * 8 + h2) * 192 + t0 + mA) * 64 + d2 +
              clA);
      }
      pW0 = *(const float2*)(cw + (long)(n0 + nB) * 512 + h2 * 64 + d2 + cl2);
    }
#pragma unroll
    for (int c = 0; c < 32; ++c) {
      acc += xs[c][m] * wsh[c][nq];
    }
    __syncthreads();
  }

  out[(long)(b * 192 + t0 + m) * 512 + n0 + nq] = acc + cb[n0 + nq];
}

extern "C" void kernel_launch(void* const* d_in, const int* in_sizes, int n_in,
                              void* d_out, int out_size, void* d_ws, size_t ws_size,
                              hipStream_t stream) {
  const float* x0 = (const float*)d_in[0];
  const float* x1 = (const float*)d_in[1];
  const float* x2 = (const float*)d_in[2];
  const float* qw = (const float*)d_in[3];
  const float* qb = (const float*)d_in[4];
  const float* kw = (const float*)d_in[5];
  const float* kb = (const float*)d_in[6];
  const float* vw = (const float*)d_in[7];
  const float* vb = (const float*)d_in[8];
  const float* cw = (const float*)d_in[9];
  const float* cb = (const float*)d_in[10];
  float* out = (float*)d_out;

  // workspace carve
  char* ws = (char*)d_ws;
  u16* Q0h = (u16*)(ws + 0);            // 16*192*64 f16 (pre-scaled by ESC)
  u16* K1h = (u16*)(ws + 393216);       // 16*192*64 f16
  float* V1f = (float*)(ws + 786432);   // 16*192*64 f32
  u16* K2b = (u16*)(ws + 1572864);      // 16*192*64 f16
  u16* V2b = (u16*)(ws + 1966080);      // 16*192*64 f16
  float* Op = (float*)(ws + 2359296);   // SPLIT*16*192*64 f32 = 6291456 B
  float* lp = (float*)(ws + 2359296 + (size_t)SPLIT * 786432);  // SPLIT*16*192 f32

  proj_kernel<<<960, 256, 0, stream>>>(x0, x1, x2, qw, qb, kw, kb, vw, vb,
                                       Q0h, K1h, V1f, K2b, V2b);
  attn_kernel<<<SPLIT * 192, 256, 0, stream>>>(Q0h, K1h, V1f, K2b, V2b,
                                               Op, lp);
  outproj_kernel<<<768, 256, 0, stream>>>(Op, lp, cw, cb, out);
}

// Round 14
// 146.503 us; speedup vs baseline: 1.1256x; 1.1256x over previous
//
#include <hip/hip_runtime.h>

typedef float f4v __attribute__((ext_vector_type(4)));
typedef _Float16 h2v __attribute__((ext_vector_type(2)));
typedef _Float16 h4v __attribute__((ext_vector_type(4)));
typedef _Float16 h8v __attribute__((ext_vector_type(8)));
typedef __fp16 g4 __attribute__((ext_vector_type(4)));
typedef __fp16 g8 __attribute__((ext_vector_type(8)));
typedef unsigned short u16;
typedef unsigned int u32;

// B=2, T=192, C=512, H=8, HS=64, ORDER=3; scale = 1/sqrt(64) = 0.125
#define SPLIT 8
#define ESC 0.18033688011112042f  // 0.125 * log2(e), folded into Q at proj

__device__ __forceinline__ h2v pkh(float lo, float hi) {
  return __builtin_bit_cast(h2v, __builtin_amdgcn_cvt_pkrtz(lo, hi));
}
__device__ __forceinline__ f4v mfma_k32(h8v a, h8v b, f4v c) {
  return __builtin_amdgcn_mfma_f32_16x16x32_f16(
      __builtin_bit_cast(g8, a), __builtin_bit_cast(g8, b), c, 0, 0, 0);
}
__device__ __forceinline__ f4v mfma_k16(h4v a, h4v b, f4v c) {
  return __builtin_amdgcn_mfma_f32_16x16x16f16(
      __builtin_bit_cast(g4, a), __builtin_bit_cast(g4, b), c, 0, 0, 0);
}

// ---------------- prep kernel: f32 -> f16 for proj inputs ----------------
// Converts x0,x1,x2 (3 x 196608 elems) and qw,kw,vw (3 x 786432 elems)
// into xh / wh.  1474560 float2 pairs, grid-stride.  ~7 MB traffic.
__global__ __launch_bounds__(256) void prep_kernel(
    const float* __restrict__ x0, const float* __restrict__ x1,
    const float* __restrict__ x2,
    const float* __restrict__ qw, const float* __restrict__ kw,
    const float* __restrict__ vw,
    u16* __restrict__ xh, u16* __restrict__ wh) {
  int i = blockIdx.x * 256 + threadIdx.x;  // pair index
  const int total = 1474560;
  for (; i < total; i += gridDim.x * 256) {
    const float* s; int off; u16* d;
    if (i < 294912) {
      int seg = i / 98304;
      s = seg == 0 ? x0 : seg == 1 ? x1 : x2;
      off = i - seg * 98304;
      d = xh + seg * 196608;
    } else {
      int j = i - 294912;
      int seg = j / 393216;
      s = seg == 0 ? qw : seg == 1 ? kw : vw;
      off = j - seg * 393216;
      d = wh + seg * 786432;
    }
    float2 v = *(const float2*)(s + (long)off * 2);
    *(u32*)(d + (long)off * 2) = __builtin_bit_cast(u32, pkh(v.x, v.y));
  }
}

// ---------------- projection kernel (MFMA, no LDS, no barriers) ----------
// 3840 wave-tasks (5 slots x 16 bh x 12 t-tiles x 4 d-tiles), grid 960 x
// 256 (4 independent waves/block).  Each wave: one 16t x 16d tile, K=512
// as 16 chained mfma_f32_16x16x32_f16 with fragments loaded DIRECT from
// global/L2 (same pattern as attn's k2f loads).  Replaces the 44us
// barrier-serialized f32 kernel (r13: VALUBusy 14%, 85% stall).
// D layout: col(l15)=t, row(quad*4+r)=d -> 4 consecutive d per lane.
__global__ __launch_bounds__(256) void proj_kernel(
    const u16* __restrict__ xh, const u16* __restrict__ wh,
    const float* __restrict__ qb, const float* __restrict__ kb,
    const float* __restrict__ vb,
    u16* __restrict__ Q0h, u16* __restrict__ K1h, float* __restrict__ V1f,
    u16* __restrict__ K2b, u16* __restrict__ V2b) {
  int g = blockIdx.x * 4 + (threadIdx.x >> 6);
  int lane = threadIdx.x & 63;
  int l15 = lane & 15, quad = lane >> 4;
  int slot = g / 768;
  int rem = g - slot * 768;
  int bh = rem / 48;
  int r2 = rem - bh * 48;
  int tt = r2 >> 2, dt = r2 & 3;
  int b = bh >> 3, h = bh & 7;

  int xsel, o, wsel;
  const float* bias;
  float* outf = nullptr; u16* outb = nullptr;
  switch (slot) {
    case 0: xsel = 0; o = 0; wsel = 0; bias = qb; outb = Q0h; break;
    case 1: xsel = 1; o = 1; wsel = 1; bias = kb; outb = K1h; break;
    case 2: xsel = 2; o = 2; wsel = 1; bias = kb; outb = K2b; break;
    case 3: xsel = 1; o = 1; wsel = 2; bias = vb; outf = V1f; break;
    default: xsel = 2; o = 2; wsel = 2; bias = vb; outb = V2b; break;
  }
  const u16* xp = xh + (long)xsel * 196608 +
                  ((long)(b * 192 + tt * 16 + l15)) * 512;
  const u16* wp = wh + (long)wsel * 786432 +
                  ((long)((h * 3 + o) * 64 + dt * 16 + l15)) * 512;
  bias += (h * 3 + o) * 64 + dt * 16;

  f4v acc = {0.f, 0.f, 0.f, 0.f};
#pragma unroll 4
  for (int kc = 0; kc < 16; ++kc) {
    h8v a = *(const h8v*)(wp + kc * 32 + quad * 8);   // A: w rows (i=d)
    h8v bf = *(const h8v*)(xp + kc * 32 + quad * 8);  // B: x cols (j=t)
    acc = mfma_k32(a, bf, acc);
  }

  float4 b4 = *(const float4*)(bias + quad * 4);
  int t = tt * 16 + l15;
  int d = dt * 16 + quad * 4;
  long base = ((long)(bh * 192 + t)) * 64 + d;
  float o0 = acc[0] + b4.x, o1 = acc[1] + b4.y;
  float o2 = acc[2] + b4.z, o3 = acc[3] + b4.w;
  if (slot == 0) { o0 *= ESC; o1 *= ESC; o2 *= ESC; o3 *= ESC; }
  if (outf) {
    float4 st = {o0, o1, o2, o3};
    *(float4*)(outf + base) = st;
  } else {
    uint2 st = {__builtin_bit_cast(u32, pkh(o0, o1)),
                __builtin_bit_cast(u32, pkh(o2, o3))};
    *(uint2*)(outb + base) = st;
  }
}

// ---------------- attention kernel ----------------
// grid = SPLIT*16*12 = 1536 blocks, 256 threads (4 waves), LDS = 25856 B.
// BYTE-IDENTICAL to the round-12/13 PASS (single S/P chain; ILP-doubling
// variants miscompile -- rounds 3/4/7/8).  Operand-swapped scores keep P
// in registers; V2T region recycled for the K1/V1 LDS stage.
__global__ __launch_bounds__(256, 4) void attn_kernel(
    const u16* __restrict__ Q0h, const u16* __restrict__ K1h,
    const float* __restrict__ V1f, const u16* __restrict__ K2b,
    const u16* __restrict__ V2b, float* __restrict__ Op,
    float* __restrict__ lp) {
  __shared__ __align__(16) char smem[25856];
  int bx = blockIdx.x;
  int sp = bx / 192;
  int rem = bx - sp * 192;
  int bh = rem / 12;
  int itile = rem - bh * 12;
  int i0 = itile * 16;
  int js = sp * 24;
  int tid = threadIdx.x;
  int wave = tid >> 6;
  int lane = tid & 63;
  int l15 = lane & 15;
  int quad = lane >> 4;

  // K1s/V1s live in the recycled V2T region after the v2g reads.
  u16* K1s = (u16*)smem;                // [24 j][64 d] u16 f16, 3072 B
  float* V1s = (float*)(smem + 3072);   // [24 j][64 d] f32, 6144 B

  // ---- early register staging of K1/V1 (latency overlaps V2T stage)
  u32 kreg0, kreg1, kreg2;
  float2 vreg0, vreg1, vreg2;
  {
    const u32* ksrc = (const u32*)(K1h + (bh * 192 + js) * 64);  // 768 u32
    kreg0 = ksrc[tid]; kreg1 = ksrc[256 + tid]; kreg2 = ksrc[512 + tid];
    const float2* vsrc2 = (const float2*)(V1f + (bh * 192 + js) * 64);
    vreg0 = vsrc2[tid]; vreg1 = vsrc2[256 + tid]; vreg2 = vsrc2[512 + tid];
  }

  // ---- prologue: stage V2^T [64 d][202 pad] u16 (natural k order)
  u16* V2T = (u16*)smem;
  {
    const u32* vsrc = (const u32*)V2b + bh * 6144;
#pragma unroll
    for (int r = 0; r < 24; ++r) {
      int idx = r * 256 + tid;
      int k = idx >> 5, d2 = idx & 31;
      u32 v = vsrc[idx];
      V2T[(d2 * 2) * 202 + k] = (u16)v;
      V2T[(d2 * 2 + 1) * 202 + k] = (u16)(v >> 16);
    }
  }
  // K2 A-fragments straight from global (rows k = w*48+nt*16+l15, kdim d)
  h8v k2f[3][2];
#pragma unroll
  for (int nt = 0; nt < 3; ++nt)
#pragma unroll
    for (int ks = 0; ks < 2; ++ks)
      k2f[nt][ks] = *(const h8v*)(K2b +
          (bh * 192 + wave * 48 + nt * 16 + l15) * 64 + ks * 32 + quad * 8);
  // Q B-fragments (kdim d = quad*8+idx (+32), col i = l15), pre-scaled ESC
  const u16* qq = Q0h + (bh * 192 + i0 + l15) * 64 + quad * 8;
  h8v qh0 = *(const h8v*)qq;
  h8v qh1 = *(const h8v*)(qq + 32);
  __syncthreads();
  // V2 B-frags for PV: grp0 k = w48+{quad*4+0..3, 16+quad*4+0..3},
  // grp1 k = w48+32+quad*4+0..3; col d = dt*16+l15.  u32 reads (stride
  // 404 B is only 4B-aligned for odd d).
  h8v v2g0[4]; h4v v2g1[4];
#pragma unroll
  for (int dt = 0; dt < 4; ++dt) {
    const char* p = smem + (dt * 16 + l15) * 404 + wave * 96 + quad * 8;
    union { h8v v; u32 w[4]; } u0;
    u0.w[0] = *(const u32*)p;        u0.w[1] = *(const u32*)(p + 4);
    u0.w[2] = *(const u32*)(p + 32); u0.w[3] = *(const u32*)(p + 36);
    v2g0[dt] = u0.v;
    union { h4v v; u32 w[2]; } u1;
    u1.w[0] = *(const u32*)(p + 64); u1.w[1] = *(const u32*)(p + 68);
    v2g1[dt] = u1.v;
  }
  __syncthreads();  // v2g in regs; V2T region now dead -> recycle
  // write K1/V1 from staging registers into the recycled region
  ((u32*)K1s)[tid] = kreg0;
  ((u32*)K1s)[256 + tid] = kreg1;
  ((u32*)K1s)[512 + tid] = kreg2;
  ((float2*)V1s)[tid] = vreg0;
  ((float2*)V1s)[256 + tid] = vreg1;
  ((float2*)V1s)[512 + tid] = vreg2;
  __syncthreads();  // K1s/V1s staged

  f4v Oacc[4] = {};
  float lsum = 0.f;
  const f4v z = {0.f, 0.f, 0.f, 0.f};

#pragma unroll 1
  for (int j = 0; j < 24; ++j) {
    // B-frag of S^T: Q~[i,d]*K1[j,d] via packed f16 mul (K1 from LDS)
    h8v c0 = *(const h8v*)(K1s + j * 64 + quad * 8);
    h8v c1 = *(const h8v*)(K1s + j * 64 + 32 + quad * 8);
    h8v B0 = qh0 * c0, B1 = qh1 * c1;
    // S^T[k=w48+nt*16+quad*4+r][i=l15], sum over d=0..63
    f4v s0 = mfma_k32(k2f[0][0], B0, z);
    f4v s1 = mfma_k32(k2f[1][0], B0, z);
    f4v s2 = mfma_k32(k2f[2][0], B0, z);
    s0 = mfma_k32(k2f[0][1], B1, s0);
    s1 = mfma_k32(k2f[1][1], B1, s1);
    s2 = mfma_k32(k2f[2][1], B1, s2);
    float p[12];
#pragma unroll
    for (int r = 0; r < 4; ++r) {
      p[r] = __builtin_amdgcn_exp2f(s0[r]);
      p[4 + r] = __builtin_amdgcn_exp2f(s1[r]);
      p[8 + r] = __builtin_amdgcn_exp2f(s2[r]);
    }
    lsum += (((p[0] + p[1]) + (p[2] + p[3])) + ((p[4] + p[5]) + (p[6] + p[7]))) +
            ((p[8] + p[9]) + (p[10] + p[11]));
    // P already in A-fragment layout: row i=l15, k in (quad, idx)
    union { h8v v; h2v h[4]; } pa0;
    pa0.h[0] = pkh(p[0], p[1]);  pa0.h[1] = pkh(p[2], p[3]);
    pa0.h[2] = pkh(p[4], p[5]);  pa0.h[3] = pkh(p[6], p[7]);
    union { h4v v; h2v h[2]; } pa1;
    pa1.h[0] = pkh(p[8], p[9]);  pa1.h[1] = pkh(p[10], p[11]);
    float v1r0 = V1s[j * 64 + l15];
    float v1r1 = V1s[j * 64 + 16 + l15];
    float v1r2 = V1s[j * 64 + 32 + l15];
    float v1r3 = V1s[j * 64 + 48 + l15];
    // W_j[i,d] over this wave's 48 k, then O += V1[j,d]*W_j
#pragma unroll
    for (int dt = 0; dt < 4; ++dt) {
      f4v w = mfma_k32(pa0.v, v2g0[dt], z);
      w = mfma_k16(pa1.v, v2g1[dt], w);
      float v1x = dt == 0 ? v1r0 : dt == 1 ? v1r1 : dt == 2 ? v1r2 : v1r3;
      Oacc[dt][0] = fmaf(v1x, w[0], Oacc[dt][0]);
      Oacc[dt][1] = fmaf(v1x, w[1], Oacc[dt][1]);
      Oacc[dt][2] = fmaf(v1x, w[2], Oacc[dt][2]);
      Oacc[dt][3] = fmaf(v1x, w[3], Oacc[dt][3]);
    }
  }

  // ---- epilogue: cross-wave k-slice reduction of O and l
  __syncthreads();  // all waves done; smem free
  float* ored = (float*)smem;            // 4 waves x [16 i][64 d] f32
  float* lred = (float*)(smem + 16384);  // 64 f32
  float* ow = ored + wave * 1024;
#pragma unroll
  for (int dt = 0; dt < 4; ++dt)
#pragma unroll
    for (int r = 0; r < 4; ++r)
      ow[(quad * 4 + r) * 64 + dt * 16 + l15] = Oacc[dt][r];
  lsum += __shfl_xor(lsum, 16);
  lsum += __shfl_xor(lsum, 32);
  if (quad == 0) lred[wave * 16 + l15] = lsum;
  __syncthreads();
  f4v s = *(const f4v*)(ored + tid * 4);
  s += *(const f4v*)(ored + 1024 + tid * 4);
  s += *(const f4v*)(ored + 2048 + tid * 4);
  s += *(const f4v*)(ored + 3072 + tid * 4);
  *(f4v*)(Op + ((long)(sp * 16 + bh) * 192 + i0) * 64 + tid * 4) = s;
  if (tid < 16)
    lp[(sp * 16 + bh) * 192 + i0 + tid] =
        lred[tid] + lred[16 + tid] + lred[32 + tid] + lred[48 + tid];
}

// ---------------- output projection (split-combine + 1/l fused) ----------
// grid = 24 mt(16) * 8 nt(64) = 192 blocks (r12 form -- the r13 n-split
// regressed; reverted).
__global__ __launch_bounds__(256) void outproj_kernel(
    const float* __restrict__ Op, const float* __restrict__ lp,
    const float* __restrict__ cw, const float* __restrict__ cb,
    float* __restrict__ out) {
  __shared__ float xs[32][20];   // [c][m]
  __shared__ float wsh[32][68];  // [c][n]
  __shared__ float linv[8][16];  // [h][m]
  int bx = blockIdx.x;
  int mt = bx >> 3, nt = bx & 7;
  int m0 = mt * 16;
  int b = m0 / 192;
  int t0 = m0 - b * 192;
  int n0 = nt * 64;
  int tid = threadIdx.x;

  if (tid < 128) {
    int h = tid >> 4, ml = tid & 15;
    float s = 0.f;
#pragma unroll
    for (int sp = 0; sp < SPLIT; ++sp)
      s += lp[(sp * 16 + b * 8 + h) * 192 + t0 + ml];
    linv[h][ml] = 1.0f / s;
  }

  int mA = tid >> 3, clA = (tid & 7) * 4;  // A-stage (tid<128 only)
  int nB0 = tid >> 3, nB1 = (256 + tid) >> 3;
  int m = tid >> 4, nq = tid & 15;
  float acc[4] = {};

  float4 pA[SPLIT];
  float4 pW0, pW1;
  {  // prefetch kc = 0 (h=0, d0=0)
    if (tid < 128) {
#pragma unroll
      for (int sp = 0; sp < SPLIT; ++sp)
        pA[sp] = *(const float4*)(
            Op + (long)((sp * 16 + b * 8) * 192 + t0 + mA) * 64 + clA);
    }
    pW0 = *(const float4*)(cw + (long)(n0 + nB0) * 512 + clA);
    pW1 = *(const float4*)(cw + (long)(n0 + nB1) * 512 + clA);
  }
  __syncthreads();  // linv ready

  for (int kc = 0; kc < 16; ++kc) {
    int h = kc >> 1;
    if (tid < 128) {  // combine SPLIT partials, scale 1/l, store [c][m]
      float4 s = pA[0];
#pragma unroll
      for (int sp = 1; sp < SPLIT; ++sp) {
        s.x += pA[sp].x; s.y += pA[sp].y; s.z += pA[sp].z; s.w += pA[sp].w;
      }
      float li = linv[h][mA];
      xs[clA][mA] = s.x * li; xs[clA + 1][mA] = s.y * li;
      xs[clA + 2][mA] = s.z * li; xs[clA + 3][mA] = s.w * li;
    }
    wsh[clA][nB0] = pW0.x; wsh[clA + 1][nB0] = pW0.y;
    wsh[clA + 2][nB0] = pW0.z; wsh[clA + 3][nB0] = pW0.w;
    wsh[clA][nB1] = pW1.x; wsh[clA + 1][nB1] = pW1.y;
    wsh[clA + 2][nB1] = pW1.z; wsh[clA + 3][nB1] = pW1.w;
    __syncthreads();
    if (kc < 15) {  // prefetch next kc during compute
      int h2 = (kc + 1) >> 1, d2 = ((kc + 1) & 1) * 32;
      if (tid < 128) {
#pragma unroll
        for (int sp = 0; sp < SPLIT; ++sp)
          pA[sp] = *(const float4*)(
              Op + (long)((sp * 16 + b * 8 + h2) * 192 + t0 + mA) * 64 + d2 +
              clA);
      }
      pW0 = *(const float4*)(cw + (long)(n0 + nB0) * 512 + h2 * 64 + d2 + clA);
      pW1 = *(const float4*)(cw + (long)(n0 + nB1) * 512 + h2 * 64 + d2 + clA);
    }
#pragma unroll
    for (int c = 0; c < 32; ++c) {
      float a = xs[c][m];
      float4 bv = *(const float4*)&wsh[c][nq * 4];
      acc[0] += a * bv.x; acc[1] += a * bv.y;
      acc[2] += a * bv.z; acc[3] += a * bv.w;
    }
    __syncthreads();
  }

  float4 bias = *(const float4*)(cb + n0 + nq * 4);
  float4 st;
  st.x = acc[0] + bias.x;
  st.y = acc[1] + bias.y;
  st.z = acc[2] + bias.z;
  st.w = acc[3] + bias.w;
  *(float4*)(out + (long)(b * 192 + t0 + m) * 512 + n0 + nq * 4) = st;
}

extern "C" void kernel_launch(void* const* d_in, const int* in_sizes, int n_in,
                              void* d_out, int out_size, void* d_ws, size_t ws_size,
                              hipStream_t stream) {
  const float* x0 = (const float*)d_in[0];
  const float* x1 = (const float*)d_in[1];
  const float* x2 = (const float*)d_in[2];
  const float* qw = (const float*)d_in[3];
  const float* qb = (const float*)d_in[4];
  const float* kw = (const float*)d_in[5];
  const float* kb = (const float*)d_in[6];
  const float* vw = (const float*)d_in[7];
  const float* vb = (const float*)d_in[8];
  const float* cw = (const float*)d_in[9];
  const float* cb = (const float*)d_in[10];
  float* out = (float*)d_out;

  // workspace carve
  char* ws = (char*)d_ws;
  u16* Q0h = (u16*)(ws + 0);            // 16*192*64 f16 (pre-scaled by ESC)
  u16* K1h = (u16*)(ws + 393216);       // 16*192*64 f16
  float* V1f = (float*)(ws + 786432);   // 16*192*64 f32
  u16* K2b = (u16*)(ws + 1572864);      // 16*192*64 f16
  u16* V2b = (u16*)(ws + 1966080);      // 16*192*64 f16
  float* Op = (float*)(ws + 2359296);   // SPLIT*16*192*64 f32 = 6291456 B
  float* lp = (float*)(ws + 2359296 + (size_t)SPLIT * 786432);  // SPLIT*16*192
  u16* xh = (u16*)(ws + 9437184);       // 3 x 196608 f16 (x0,x1,x2)
  u16* wh = (u16*)(ws + 9437184 + 1179648);  // 3 x 786432 f16 (qw,kw,vw)

  prep_kernel<<<1440, 256, 0, stream>>>(x0, x1, x2, qw, kw, vw, xh, wh);
  proj_kernel<<<960, 256, 0, stream>>>(xh, wh, qb, kb, vb,
                                       Q0h, K1h, V1f, K2b, V2b);
  attn_kernel<<<SPLIT * 192, 256, 0, stream>>>(Q0h, K1h, V1f, K2b, V2b,
                                               Op, lp);
  outproj_kernel<<<192, 256, 0, stream>>>(Op, lp, cw, cb, out);
}

// Round 15
// 139.873 us; speedup vs baseline: 1.1789x; 1.0474x over previous
//
#include <hip/hip_runtime.h>

typedef float f4v __attribute__((ext_vector_type(4)));
typedef _Float16 h2v __attribute__((ext_vector_type(2)));
typedef _Float16 h4v __attribute__((ext_vector_type(4)));
typedef _Float16 h8v __attribute__((ext_vector_type(8)));
typedef __fp16 g4 __attribute__((ext_vector_type(4)));
typedef __fp16 g8 __attribute__((ext_vector_type(8)));
typedef unsigned short u16;
typedef unsigned int u32;

// B=2, T=192, C=512, H=8, HS=64, ORDER=3; scale = 1/sqrt(64) = 0.125
#define SPLIT 8
#define ESC 0.18033688011112042f  // 0.125 * log2(e), folded into Q at proj

__device__ __forceinline__ h2v pkh(float lo, float hi) {
  return __builtin_bit_cast(h2v, __builtin_amdgcn_cvt_pkrtz(lo, hi));
}
__device__ __forceinline__ f4v mfma_k32(h8v a, h8v b, f4v c) {
  return __builtin_amdgcn_mfma_f32_16x16x32_f16(
      __builtin_bit_cast(g8, a), __builtin_bit_cast(g8, b), c, 0, 0, 0);
}
__device__ __forceinline__ f4v mfma_k16(h4v a, h4v b, f4v c) {
  return __builtin_amdgcn_mfma_f32_16x16x16f16(
      __builtin_bit_cast(g4, a), __builtin_bit_cast(g4, b), c, 0, 0, 0);
}

// ---------------- prep kernel: f32 -> f16 for proj/outproj inputs -------
// Converts x0,x1,x2 (3 x 196608), qw,kw,vw (3 x 786432), cw (262144).
// 1605632 float2 pairs, grid-stride.
__global__ __launch_bounds__(256) void prep_kernel(
    const float* __restrict__ x0, const float* __restrict__ x1,
    const float* __restrict__ x2,
    const float* __restrict__ qw, const float* __restrict__ kw,
    const float* __restrict__ vw, const float* __restrict__ cw,
    u16* __restrict__ xh, u16* __restrict__ wh, u16* __restrict__ cwh) {
  int i = blockIdx.x * 256 + threadIdx.x;  // pair index
  const int total = 1605632;
  for (; i < total; i += gridDim.x * 256) {
    const float* s; int off; u16* d;
    if (i < 294912) {
      int seg = i / 98304;
      s = seg == 0 ? x0 : seg == 1 ? x1 : x2;
      off = i - seg * 98304;
      d = xh + seg * 196608;
    } else if (i < 1474560) {
      int j = i - 294912;
      int seg = j / 393216;
      s = seg == 0 ? qw : seg == 1 ? kw : vw;
      off = j - seg * 393216;
      d = wh + seg * 786432;
    } else {
      s = cw; off = i - 1474560; d = cwh;
    }
    float2 v = *(const float2*)(s + (long)off * 2);
    *(u32*)(d + (long)off * 2) = __builtin_bit_cast(u32, pkh(v.x, v.y));
  }
}

// ---------------- projection kernel (MFMA, no LDS, no barriers) ----------
// 3840 wave-tasks (5 slots x 16 bh x 12 t-tiles x 4 d-tiles), grid 960 x
// 256 (4 independent waves/block).  Each wave: one 16t x 16d tile, K=512
// as 16 chained mfma_f32_16x16x32_f16, fragments DIRECT from global/L2.
// D layout: col(l15)=t, row(quad*4+r)=d -> 4 consecutive d per lane.
__global__ __launch_bounds__(256) void proj_kernel(
    const u16* __restrict__ xh, const u16* __restrict__ wh,
    const float* __restrict__ qb, const float* __restrict__ kb,
    const float* __restrict__ vb,
    u16* __restrict__ Q0h, u16* __restrict__ K1h, float* __restrict__ V1f,
    u16* __restrict__ K2b, u16* __restrict__ V2b) {
  int g = blockIdx.x * 4 + (threadIdx.x >> 6);
  int lane = threadIdx.x & 63;
  int l15 = lane & 15, quad = lane >> 4;
  int slot = g / 768;
  int rem = g - slot * 768;
  int bh = rem / 48;
  int r2 = rem - bh * 48;
  int tt = r2 >> 2, dt = r2 & 3;
  int b = bh >> 3, h = bh & 7;

  int xsel, o, wsel;
  const float* bias;
  float* outf = nullptr; u16* outb = nullptr;
  switch (slot) {
    case 0: xsel = 0; o = 0; wsel = 0; bias = qb; outb = Q0h; break;
    case 1: xsel = 1; o = 1; wsel = 1; bias = kb; outb = K1h; break;
    case 2: xsel = 2; o = 2; wsel = 1; bias = kb; outb = K2b; break;
    case 3: xsel = 1; o = 1; wsel = 2; bias = vb; outf = V1f; break;
    default: xsel = 2; o = 2; wsel = 2; bias = vb; outb = V2b; break;
  }
  const u16* xp = xh + (long)xsel * 196608 +
                  ((long)(b * 192 + tt * 16 + l15)) * 512;
  const u16* wp = wh + (long)wsel * 786432 +
                  ((long)((h * 3 + o) * 64 + dt * 16 + l15)) * 512;
  bias += (h * 3 + o) * 64 + dt * 16;

  f4v acc = {0.f, 0.f, 0.f, 0.f};
#pragma unroll 4
  for (int kc = 0; kc < 16; ++kc) {
    h8v a = *(const h8v*)(wp + kc * 32 + quad * 8);   // A: w rows (i=d)
    h8v bf = *(const h8v*)(xp + kc * 32 + quad * 8);  // B: x cols (j=t)
    acc = mfma_k32(a, bf, acc);
  }

  float4 b4 = *(const float4*)(bias + quad * 4);
  int t = tt * 16 + l15;
  int d = dt * 16 + quad * 4;
  long base = ((long)(bh * 192 + t)) * 64 + d;
  float o0 = acc[0] + b4.x, o1 = acc[1] + b4.y;
  float o2 = acc[2] + b4.z, o3 = acc[3] + b4.w;
  if (slot == 0) { o0 *= ESC; o1 *= ESC; o2 *= ESC; o3 *= ESC; }
  if (outf) {
    float4 st = {o0, o1, o2, o3};
    *(float4*)(outf + base) = st;
  } else {
    uint2 st = {__builtin_bit_cast(u32, pkh(o0, o1)),
                __builtin_bit_cast(u32, pkh(o2, o3))};
    *(uint2*)(outb + base) = st;
  }
}

// ---------------- attention kernel ----------------
// grid = SPLIT*16*12 = 1536 blocks, 256 threads (4 waves), LDS = 25856 B.
// BYTE-IDENTICAL to the round-12/13/14 PASS (single S/P chain; ILP-
// doubling variants miscompile -- rounds 3/4/7/8).  Operand-swapped
// scores keep P in registers; V2T region recycled for K1/V1 LDS stage.
__global__ __launch_bounds__(256, 4) void attn_kernel(
    const u16* __restrict__ Q0h, const u16* __restrict__ K1h,
    const float* __restrict__ V1f, const u16* __restrict__ K2b,
    const u16* __restrict__ V2b, float* __restrict__ Op,
    float* __restrict__ lp) {
  __shared__ __align__(16) char smem[25856];
  int bx = blockIdx.x;
  int sp = bx / 192;
  int rem = bx - sp * 192;
  int bh = rem / 12;
  int itile = rem - bh * 12;
  int i0 = itile * 16;
  int js = sp * 24;
  int tid = threadIdx.x;
  int wave = tid >> 6;
  int lane = tid & 63;
  int l15 = lane & 15;
  int quad = lane >> 4;

  // K1s/V1s live in the recycled V2T region after the v2g reads.
  u16* K1s = (u16*)smem;                // [24 j][64 d] u16 f16, 3072 B
  float* V1s = (float*)(smem + 3072);   // [24 j][64 d] f32, 6144 B

  // ---- early register staging of K1/V1 (latency overlaps V2T stage)
  u32 kreg0, kreg1, kreg2;
  float2 vreg0, vreg1, vreg2;
  {
    const u32* ksrc = (const u32*)(K1h + (bh * 192 + js) * 64);  // 768 u32
    kreg0 = ksrc[tid]; kreg1 = ksrc[256 + tid]; kreg2 = ksrc[512 + tid];
    const float2* vsrc2 = (const float2*)(V1f + (bh * 192 + js) * 64);
    vreg0 = vsrc2[tid]; vreg1 = vsrc2[256 + tid]; vreg2 = vsrc2[512 + tid];
  }

  // ---- prologue: stage V2^T [64 d][202 pad] u16 (natural k order)
  u16* V2T = (u16*)smem;
  {
    const u32* vsrc = (const u32*)V2b + bh * 6144;
#pragma unroll
    for (int r = 0; r < 24; ++r) {
      int idx = r * 256 + tid;
      int k = idx >> 5, d2 = idx & 31;
      u32 v = vsrc[idx];
      V2T[(d2 * 2) * 202 + k] = (u16)v;
      V2T[(d2 * 2 + 1) * 202 + k] = (u16)(v >> 16);
    }
  }
  // K2 A-fragments straight from global (rows k = w*48+nt*16+l15, kdim d)
  h8v k2f[3][2];
#pragma unroll
  for (int nt = 0; nt < 3; ++nt)
#pragma unroll
    for (int ks = 0; ks < 2; ++ks)
      k2f[nt][ks] = *(const h8v*)(K2b +
          (bh * 192 + wave * 48 + nt * 16 + l15) * 64 + ks * 32 + quad * 8);
  // Q B-fragments (kdim d = quad*8+idx (+32), col i = l15), pre-scaled ESC
  const u16* qq = Q0h + (bh * 192 + i0 + l15) * 64 + quad * 8;
  h8v qh0 = *(const h8v*)qq;
  h8v qh1 = *(const h8v*)(qq + 32);
  __syncthreads();
  // V2 B-frags for PV: grp0 k = w48+{quad*4+0..3, 16+quad*4+0..3},
  // grp1 k = w48+32+quad*4+0..3; col d = dt*16+l15.  u32 reads (stride
  // 404 B is only 4B-aligned for odd d).
  h8v v2g0[4]; h4v v2g1[4];
#pragma unroll
  for (int dt = 0; dt < 4; ++dt) {
    const char* p = smem + (dt * 16 + l15) * 404 + wave * 96 + quad * 8;
    union { h8v v; u32 w[4]; } u0;
    u0.w[0] = *(const u32*)p;        u0.w[1] = *(const u32*)(p + 4);
    u0.w[2] = *(const u32*)(p + 32); u0.w[3] = *(const u32*)(p + 36);
    v2g0[dt] = u0.v;
    union { h4v v; u32 w[2]; } u1;
    u1.w[0] = *(const u32*)(p + 64); u1.w[1] = *(const u32*)(p + 68);
    v2g1[dt] = u1.v;
  }
  __syncthreads();  // v2g in regs; V2T region now dead -> recycle
  // write K1/V1 from staging registers into the recycled region
  ((u32*)K1s)[tid] = kreg0;
  ((u32*)K1s)[256 + tid] = kreg1;
  ((u32*)K1s)[512 + tid] = kreg2;
  ((float2*)V1s)[tid] = vreg0;
  ((float2*)V1s)[256 + tid] = vreg1;
  ((float2*)V1s)[512 + tid] = vreg2;
  __syncthreads();  // K1s/V1s staged

  f4v Oacc[4] = {};
  float lsum = 0.f;
  const f4v z = {0.f, 0.f, 0.f, 0.f};

#pragma unroll 1
  for (int j = 0; j < 24; ++j) {
    // B-frag of S^T: Q~[i,d]*K1[j,d] via packed f16 mul (K1 from LDS)
    h8v c0 = *(const h8v*)(K1s + j * 64 + quad * 8);
    h8v c1 = *(const h8v*)(K1s + j * 64 + 32 + quad * 8);
    h8v B0 = qh0 * c0, B1 = qh1 * c1;
    // S^T[k=w48+nt*16+quad*4+r][i=l15], sum over d=0..63
    f4v s0 = mfma_k32(k2f[0][0], B0, z);
    f4v s1 = mfma_k32(k2f[1][0], B0, z);
    f4v s2 = mfma_k32(k2f[2][0], B0, z);
    s0 = mfma_k32(k2f[0][1], B1, s0);
    s1 = mfma_k32(k2f[1][1], B1, s1);
    s2 = mfma_k32(k2f[2][1], B1, s2);
    float p[12];
#pragma unroll
    for (int r = 0; r < 4; ++r) {
      p[r] = __builtin_amdgcn_exp2f(s0[r]);
      p[4 + r] = __builtin_amdgcn_exp2f(s1[r]);
      p[8 + r] = __builtin_amdgcn_exp2f(s2[r]);
    }
    lsum += (((p[0] + p[1]) + (p[2] + p[3])) + ((p[4] + p[5]) + (p[6] + p[7]))) +
            ((p[8] + p[9]) + (p[10] + p[11]));
    // P already in A-fragment layout: row i=l15, k in (quad, idx)
    union { h8v v; h2v h[4]; } pa0;
    pa0.h[0] = pkh(p[0], p[1]);  pa0.h[1] = pkh(p[2], p[3]);
    pa0.h[2] = pkh(p[4], p[5]);  pa0.h[3] = pkh(p[6], p[7]);
    union { h4v v; h2v h[2]; } pa1;
    pa1.h[0] = pkh(p[8], p[9]);  pa1.h[1] = pkh(p[10], p[11]);
    float v1r0 = V1s[j * 64 + l15];
    float v1r1 = V1s[j * 64 + 16 + l15];
    float v1r2 = V1s[j * 64 + 32 + l15];
    float v1r3 = V1s[j * 64 + 48 + l15];
    // W_j[i,d] over this wave's 48 k, then O += V1[j,d]*W_j
#pragma unroll
    for (int dt = 0; dt < 4; ++dt) {
      f4v w = mfma_k32(pa0.v, v2g0[dt], z);
      w = mfma_k16(pa1.v, v2g1[dt], w);
      float v1x = dt == 0 ? v1r0 : dt == 1 ? v1r1 : dt == 2 ? v1r2 : v1r3;
      Oacc[dt][0] = fmaf(v1x, w[0], Oacc[dt][0]);
      Oacc[dt][1] = fmaf(v1x, w[1], Oacc[dt][1]);
      Oacc[dt][2] = fmaf(v1x, w[2], Oacc[dt][2]);
      Oacc[dt][3] = fmaf(v1x, w[3], Oacc[dt][3]);
    }
  }

  // ---- epilogue: cross-wave k-slice reduction of O and l
  __syncthreads();  // all waves done; smem free
  float* ored = (float*)smem;            // 4 waves x [16 i][64 d] f32
  float* lred = (float*)(smem + 16384);  // 64 f32
  float* ow = ored + wave * 1024;
#pragma unroll
  for (int dt = 0; dt < 4; ++dt)
#pragma unroll
    for (int r = 0; r < 4; ++r)
      ow[(quad * 4 + r) * 64 + dt * 16 + l15] = Oacc[dt][r];
  lsum += __shfl_xor(lsum, 16);
  lsum += __shfl_xor(lsum, 32);
  if (quad == 0) lred[wave * 16 + l15] = lsum;
  __syncthreads();
  f4v s = *(const f4v*)(ored + tid * 4);
  s += *(const f4v*)(ored + 1024 + tid * 4);
  s += *(const f4v*)(ored + 2048 + tid * 4);
  s += *(const f4v*)(ored + 3072 + tid * 4);
  *(f4v*)(Op + ((long)(sp * 16 + bh) * 192 + i0) * 64 + tid * 4) = s;
  if (tid < 16)
    lp[(sp * 16 + bh) * 192 + i0 + tid] =
        lred[tid] + lred[16 + tid] + lred[32 + tid] + lred[48 + tid];
}

// ---------------- combine kernel: Op/lp -> normalized xnorm f16 ----------
// xnorm[b*192+t][h*64+d] = (sum_sp Op[sp][bh][t][d]) / (sum_sp lp[...]).
// 98304 u32 pairs, 384 blocks x 256, no barriers.  Same sp-summation
// order as the old outproj combine.
__global__ __launch_bounds__(256) void combine_kernel(
    const float* __restrict__ Op, const float* __restrict__ lp,
    u16* __restrict__ xh2) {
  int idx = blockIdx.x * 256 + threadIdx.x;  // pair index
  int row = idx >> 8;          // 0..383 = b*192+t
  int cp = idx & 255;          // c = cp*2
  int b = row / 192, t = row - b * 192;
  int c = cp * 2;
  int h = c >> 6, d = c & 63;
  float sx = 0.f, sy = 0.f, l = 0.f;
#pragma unroll
  for (int sp = 0; sp < SPLIT; ++sp) {
    int rowp = (sp * 16 + b * 8 + h) * 192 + t;
    float2 v = *(const float2*)(Op + (long)rowp * 64 + d);
    sx += v.x; sy += v.y;
    l += lp[rowp];
  }
  float li = 1.0f / l;
  *(u32*)(xh2 + (long)row * 512 + c) =
      __builtin_bit_cast(u32, pkh(sx * li, sy * li));
}

// ---------------- output projection (MFMA, no LDS, no barriers) ----------
// 768 wave-tasks (24 t-tiles x 32 n-tiles), grid 192 x 256 (4 waves).
// Each wave: one 16t x 16n tile, K=512 as 16 chained mfma with A = cwh
// rows (i=n) and B = xh2 rows (j=t) -- replaces the 0.75-blocks/CU
// barrier-serialized r12 kernel (same pathology as the old proj).
__global__ __launch_bounds__(256) void outproj_kernel(
    const u16* __restrict__ xh2, const u16* __restrict__ cwh,
    const float* __restrict__ cb, float* __restrict__ out) {
  int g = blockIdx.x * 4 + (threadIdx.x >> 6);  // 0..767
  int lane = threadIdx.x & 63;
  int l15 = lane & 15, quad = lane >> 4;
  int mt = g >> 5, nt = g & 31;
  const u16* ap = cwh + ((long)(nt * 16 + l15)) * 512;  // A: cw rows (i=n)
  const u16* bp = xh2 + ((long)(mt * 16 + l15)) * 512;  // B: xnorm rows (j=t)
  f4v acc = {0.f, 0.f, 0.f, 0.f};
#pragma unroll 4
  for (int kc = 0; kc < 16; ++kc) {
    h8v a = *(const h8v*)(ap + kc * 32 + quad * 8);
    h8v bf = *(const h8v*)(bp + kc * 32 + quad * 8);
    acc = mfma_k32(a, bf, acc);
  }
  float4 b4 = *(const float4*)(cb + nt * 16 + quad * 4);
  int t = mt * 16 + l15;
  long base = (long)t * 512 + nt * 16 + quad * 4;
  float4 st = {acc[0] + b4.x, acc[1] + b4.y, acc[2] + b4.z, acc[3] + b4.w};
  *(float4*)(out + base) = st;
}

extern "C" void kernel_launch(void* const* d_in, const int* in_sizes, int n_in,
                              void* d_out, int out_size, void* d_ws, size_t ws_size,
                              hipStream_t stream) {
  const float* x0 = (const float*)d_in[0];
  const float* x1 = (const float*)d_in[1];
  const float* x2 = (const float*)d_in[2];
  const float* qw = (const float*)d_in[3];
  const float* qb = (const float*)d_in[4];
  const float* kw = (const float*)d_in[5];
  const float* kb = (const float*)d_in[6];
  const float* vw = (const float*)d_in[7];
  const float* vb = (const float*)d_in[8];
  const float* cw = (const float*)d_in[9];
  const float* cb = (const float*)d_in[10];
  float* out = (float*)d_out;

  // workspace carve
  char* ws = (char*)d_ws;
  u16* Q0h = (u16*)(ws + 0);            // 16*192*64 f16 (pre-scaled by ESC)
  u16* K1h = (u16*)(ws + 393216);       // 16*192*64 f16
  float* V1f = (float*)(ws + 786432);   // 16*192*64 f32
  u16* K2b = (u16*)(ws + 1572864);      // 16*192*64 f16
  u16* V2b = (u16*)(ws + 1966080);      // 16*192*64 f16
  float* Op = (float*)(ws + 2359296);   // SPLIT*16*192*64 f32 = 6291456 B
  float* lp = (float*)(ws + 2359296 + (size_t)SPLIT * 786432);  // SPLIT*16*192
  u16* xh = (u16*)(ws + 9437184);       // 3 x 196608 f16 (x0,x1,x2)
  u16* wh = (u16*)(ws + 10616832);      // 3 x 786432 f16 (qw,kw,vw)
  u16* cwh = (u16*)(ws + 15335424);     // 262144 f16 (cw)
  u16* xh2 = (u16*)(ws + 15859712);     // 384*512 f16 (normalized attn out)

  prep_kernel<<<1440, 256, 0, stream>>>(x0, x1, x2, qw, kw, vw, cw,
                                        xh, wh, cwh);
  proj_kernel<<<960, 256, 0, stream>>>(xh, wh, qb, kb, vb,
                                       Q0h, K1h, V1f, K2b, V2b);
  attn_kernel<<<SPLIT * 192, 256, 0, stream>>>(Q0h, K1h, V1f, K2b, V2b,
                                               Op, lp);
  combine_kernel<<<384, 256, 0, stream>>>(Op, lp, xh2);
  outproj_kernel<<<192, 256, 0, stream>>>(xh2, cwh, cb, out);
}